// Round 7
// baseline (82.769 us; speedup 1.0000x reference)
//
#include <hip/hip_runtime.h>

#define N_NODES 100000
#define E_EDGES 2000000
#define SPLIT_E 1800000   // top 10%: 400k touches, P(node untouched) ~ e^-4 ~ 1.8%
#define CIN 16
#define EXH_FLOW 4.0f     // 0.0001 * 40000
#define TOP_E (E_EDGES - SPLIT_E)

#define BLK 256
#define FLOW_THREADS (E_EDGES * 4)                 // 4 lanes per edge
#define FLOW_BLOCKS  (FLOW_THREADS / BLK)          // 31250
#define SCAT_EPT 8                                  // edges per scatter thread
#define SCAT_THREADS (SPLIT_E / SCAT_EPT)           // 225000
#define SCAT_BLOCKS  ((SCAT_THREADS + BLK - 1) / BLK)

// origin_data: (N, 8, 3) f32; last timestep at n*24 + {21,22,23} = {conc, people, size}

// K1: node init + table init (in-kernel stores — R6 lesson: memset nodes cost
// more than fused stores).
__global__ void init_nodes_kernel(const float* __restrict__ origin,
                                  float* __restrict__ out,
                                  int* __restrict__ max_ord,
                                  float* __restrict__ conc_c,
                                  float* __restrict__ rsize_c,
                                  unsigned char* __restrict__ settled) {
    int n = blockIdx.x * blockDim.x + threadIdx.x;
    if (n >= N_NODES) return;
    size_t base = (size_t)n * 24;
    float conc   = origin[base + 21];
    float people = origin[base + 22];
    float size   = origin[base + 23];
    float rs = 1.0f / size;
    out[n] = conc + EXH_FLOW * people * rs;
    conc_c[n]  = conc;
    rsize_c[n] = rs;
    max_ord[n] = -1;
    settled[n] = 0;
}

// K2: top chunk — pure atomics (values unsettled here; R2 lesson) + mark
// settled: top orders >= 2*SPLIT_E dominate all lower orders, so these nodes'
// maxes are FINAL after this dispatch. Same-value byte races benign.
__global__ void scatter_top_kernel(const int* __restrict__ src,
                                   const int* __restrict__ dst,
                                   int* __restrict__ max_ord,
                                   unsigned char* __restrict__ settled) {
    int i = blockIdx.x * blockDim.x + threadIdx.x;
    int e = SPLIT_E + i;
    if (e >= E_EDGES) return;
    int s = src[e], d = dst[e];
    if (s != d) {
        atomicMax(&max_ord[s], 2 * e);
        atomicMax(&max_ord[d], 2 * e + 1);
        settled[s] = 1;
        settled[d] = 1;
    }
}

// K3: block-role split — BW-bound stream blocks + latency-bound scatter blocks
// co-resident in ONE dispatch (complementary resources; scatter stalls hide
// under stream BW, no extra kernel boundary).
__global__ void main_pass_kernel(const float4* __restrict__ xv,
                                 const float* __restrict__ w,
                                 const float* __restrict__ b,
                                 const int* __restrict__ src,
                                 const int* __restrict__ dst,
                                 const unsigned char* __restrict__ settled,
                                 float* __restrict__ flow,
                                 int* __restrict__ max_ord) {
    if (blockIdx.x < FLOW_BLOCKS) {
        // Pure coalesced stream: 4 lanes/edge, one float4 each, shfl reduce.
        int tid = blockIdx.x * BLK + threadIdx.x;      // < 8M exactly
        int q = tid & 3;
        float4 v  = xv[tid];
        float4 wq = ((const float4*)w)[q];             // 64B, L1 broadcast
        float p = v.x * wq.x + v.y * wq.y + v.z * wq.z + v.w * wq.w;
        p += __shfl_xor(p, 1);
        p += __shfl_xor(p, 2);
        if (q == 0) flow[tid >> 2] = p + b[0];         // 16 lanes/wave, 64B
    } else {
        // Scatter over [0, SPLIT_E): precheck against the IMMUTABLE settled
        // map (100 KB, read-only here -> L2-hot, never invalidated; the ~66k
        // firing atomics hit a different array). 8 edges/thread, int4 loads.
        int t = (blockIdx.x - FLOW_BLOCKS) * BLK + threadIdx.x;
        int e0 = t * SCAT_EPT;
        if (e0 >= SPLIT_E) return;
        int4 sa = *(const int4*)(src + e0);
        int4 sb = *(const int4*)(src + e0 + 4);
        int4 da = *(const int4*)(dst + e0);
        int4 db = *(const int4*)(dst + e0 + 4);
#define PROC(EE, SS, DD)                                                  \
        if ((SS) != (DD)) {                                               \
            if (!settled[SS]) atomicMax(&max_ord[SS], 2 * (EE));          \
            if (!settled[DD]) atomicMax(&max_ord[DD], 2 * (EE) + 1);      \
        }
        PROC(e0 + 0, sa.x, da.x)
        PROC(e0 + 1, sa.y, da.y)
        PROC(e0 + 2, sa.z, da.z)
        PROC(e0 + 3, sa.w, da.w)
        PROC(e0 + 4, sb.x, db.x)
        PROC(e0 + 5, sb.y, db.y)
        PROC(e0 + 6, sb.z, db.z)
        PROC(e0 + 7, sb.w, db.w)
#undef PROC
    }
}

// K4: per-node finalize — decode winning occurrence, gather its value.
__global__ void finalize_kernel(const int* __restrict__ src,
                                const float* __restrict__ flow,
                                const int* __restrict__ max_ord,
                                const float* __restrict__ conc_c,
                                const float* __restrict__ rsize_c,
                                float* __restrict__ out) {
    int n = blockIdx.x * blockDim.x + threadIdx.x;
    if (n >= N_NODES) return;
    int o = max_ord[n];
    if (o < 0) return;
    int e = o >> 1;
    float val = flow[e];
    float v;
    if ((o & 1) == 0) {
        v = val * conc_c[n] * rsize_c[n];            // src-side: src[e]==n
    } else {
        int s = src[e];
        v = val * conc_c[s] * rsize_c[n];            // dst-side
    }
    out[n] += v;
}

extern "C" void kernel_launch(void* const* d_in, const int* in_sizes, int n_in,
                              void* d_out, int out_size, void* d_ws, size_t ws_size,
                              hipStream_t stream) {
    const float* origin = (const float*)d_in[0];   // (N, 8, 3)
    const float* x      = (const float*)d_in[1];   // (E, 1, 16)
    const float* conv_w = (const float*)d_in[2];   // (1, 16, 1, 1)
    const float* conv_b = (const float*)d_in[3];   // (1,)
    const int*   eidx   = (const int*)d_in[4];     // (2, E)
    const int* src = eidx;
    const int* dst = eidx + E_EDGES;

    float* out  = (float*)d_out;          // [0, N): result; [N, N+E): flow
    float* flow = out + N_NODES;

    int*           max_ord = (int*)d_ws;                           // 400 KB
    float*         conc_c  = (float*)((char*)d_ws + 1 * 400 * 1024);
    float*         rsize_c = (float*)((char*)d_ws + 2 * 400 * 1024);
    unsigned char* settled = (unsigned char*)((char*)d_ws + 3 * 400 * 1024); // 100 KB

    init_nodes_kernel<<<(N_NODES + BLK - 1) / BLK, BLK, 0, stream>>>(
        origin, out, max_ord, conc_c, rsize_c, settled);
    scatter_top_kernel<<<(TOP_E + BLK - 1) / BLK, BLK, 0, stream>>>(
        src, dst, max_ord, settled);
    main_pass_kernel<<<FLOW_BLOCKS + SCAT_BLOCKS, BLK, 0, stream>>>(
        (const float4*)x, conv_w, conv_b, src, dst, settled, flow, max_ord);
    finalize_kernel<<<(N_NODES + BLK - 1) / BLK, BLK, 0, stream>>>(
        src, flow, max_ord, conc_c, rsize_c, out);
}